// Round 1
// baseline (139.614 us; speedup 1.0000x reference)
//
#include <hip/hip_runtime.h>

// LocalConv: out[b][o][oh][ow] = sum_f patch[p][b][f] * W[p][f][o]
// B=64, C=16, H=W=64, K=3x3, OH=OW=62, OUT_CH=32, FEAT=144, P=3844
#define BATCH 64
#define CIN   16
#define HH    64
#define WW    64
#define OHD   62
#define OWD   62
#define OUTC  32
#define FEATN 144
#define KPAD  160   // FEAT padded to 5 K-chunks of 32
#define LSTR  168   // LDS row stride (bf16 elems): 336B, multiple of 16B, bank-friendly

typedef __attribute__((ext_vector_type(8))) short  short8;
typedef __attribute__((ext_vector_type(4))) float  f32x4;

__device__ __forceinline__ unsigned short f2bf(float f) {
    unsigned int u = __float_as_uint(f);
    u += 0x7FFFu + ((u >> 16) & 1u);   // RNE
    return (unsigned short)(u >> 16);
}

__global__ __launch_bounds__(256) void localconv_kernel(
    const float* __restrict__ inp,   // [64][16][64][64]
    const float* __restrict__ wgt,   // [P][144][32]
    float* __restrict__ out)         // [64][32][62][62]
{
    __shared__ unsigned short A_lds[BATCH * LSTR];  // 21504 B: patches, bf16
    __shared__ unsigned short B_lds[OUTC * LSTR];   // 10752 B: weights^T, bf16

    const int p   = blockIdx.x;
    const int oh  = p / OWD;
    const int ow  = p - oh * OWD;
    const int tid = threadIdx.x;

    // ---- stage weights: W[p][f][o] fp32 -> B_lds[o][f] bf16 (coalesced float4 reads)
    {
        const f32x4* w4 = (const f32x4*)(wgt + (size_t)p * (FEATN * OUTC));
        for (int idx = tid; idx < (FEATN * OUTC / 4); idx += 256) {
            f32x4 v = w4[idx];
            int f  = idx >> 3;            // 8 float4 per f row (OUTC=32)
            int o0 = (idx & 7) << 2;
            B_lds[(o0 + 0) * LSTR + f] = f2bf(v[0]);
            B_lds[(o0 + 1) * LSTR + f] = f2bf(v[1]);
            B_lds[(o0 + 2) * LSTR + f] = f2bf(v[2]);
            B_lds[(o0 + 3) * LSTR + f] = f2bf(v[3]);
        }
    }

    // ---- stage patches: inp[b][c][oh+kh][ow+kw] -> A_lds[b][c*9 + kh*3 + kw]
    for (int pair = tid; pair < BATCH * CIN; pair += 256) {
        int b = pair >> 4, c = pair & 15;
        const float* src = inp + (((size_t)(b * CIN + c) * HH + oh) * WW + ow);
        unsigned short* dst = &A_lds[b * LSTR + c * 9];
        #pragma unroll
        for (int kh = 0; kh < 3; ++kh) {
            float v0 = src[kh * WW + 0];
            float v1 = src[kh * WW + 1];
            float v2 = src[kh * WW + 2];
            dst[kh * 3 + 0] = f2bf(v0);
            dst[kh * 3 + 1] = f2bf(v1);
            dst[kh * 3 + 2] = f2bf(v2);
        }
    }

    // ---- zero-pad K range [144,160)
    for (int idx = tid; idx < BATCH * (KPAD - FEATN); idx += 256)
        A_lds[(idx >> 4) * LSTR + FEATN + (idx & 15)] = 0;
    for (int idx = tid; idx < OUTC * (KPAD - FEATN); idx += 256)
        B_lds[(idx >> 4) * LSTR + FEATN + (idx & 15)] = 0;

    __syncthreads();

    // ---- MFMA: wave w computes rows [16w,16w+16) x all 32 cols
    const int wid  = tid >> 6;
    const int lane = tid & 63;
    const int fr   = lane & 15;     // frag row/col index
    const int fq   = lane >> 4;     // frag k-quad

    f32x4 acc0 = {0.f, 0.f, 0.f, 0.f};
    f32x4 acc1 = {0.f, 0.f, 0.f, 0.f};

    #pragma unroll
    for (int kc = 0; kc < 5; ++kc) {
        const int koff = kc * 32 + fq * 8;
        short8 a  = *(const short8*)&A_lds[(wid * 16 + fr) * LSTR + koff];
        short8 b0 = *(const short8*)&B_lds[fr * LSTR + koff];
        short8 b1 = *(const short8*)&B_lds[(16 + fr) * LSTR + koff];
        acc0 = __builtin_amdgcn_mfma_f32_16x16x32_bf16(a, b0, acc0, 0, 0, 0);
        acc1 = __builtin_amdgcn_mfma_f32_16x16x32_bf16(a, b1, acc1, 0, 0, 0);
    }

    // ---- write C: D layout col=lane&15, row=4*(lane>>4)+reg
    const int brow = wid * 16 + fq * 4;
    const size_t sp = (size_t)oh * OWD + ow;
    #pragma unroll
    for (int r = 0; r < 4; ++r) {
        size_t base = ((size_t)(brow + r) * OUTC) * (size_t)(OHD * OWD) + sp;
        out[base + (size_t)fr * (OHD * OWD)]        = acc0[r];
        out[base + (size_t)(16 + fr) * (OHD * OWD)] = acc1[r];
    }
}

extern "C" void kernel_launch(void* const* d_in, const int* in_sizes, int n_in,
                              void* d_out, int out_size, void* d_ws, size_t ws_size,
                              hipStream_t stream) {
    const float* inp = (const float*)d_in[0];
    const float* wgt = (const float*)d_in[1];
    float* out = (float*)d_out;
    dim3 grid(OHD * OWD);
    localconv_kernel<<<grid, 256, 0, stream>>>(inp, wgt, out);
}